// Round 9
// baseline (292.027 us; speedup 1.0000x reference)
//
#include <hip/hip_runtime.h>
#include <hip/hip_bf16.h>

typedef unsigned short u16;
typedef __attribute__((ext_vector_type(8))) short bf16x8;
typedef __attribute__((ext_vector_type(4))) short short4v;
typedef __attribute__((ext_vector_type(4))) float floatx4;
typedef __attribute__((ext_vector_type(2))) unsigned uint2v;
typedef __attribute__((ext_vector_type(4))) unsigned uint4v;

__device__ __forceinline__ float bf2f(u16 u) {
    unsigned v = ((unsigned)u) << 16;
    return __builtin_bit_cast(float, v);
}
__device__ __forceinline__ u16 f2bf(float f) {
    unsigned u = __builtin_bit_cast(unsigned, f);
    u += 0x7fffu + ((u >> 16) & 1u);   // RNE
    return (u16)(u >> 16);
}

#define GLDS16(g, l)                                                             \
    __builtin_amdgcn_global_load_lds(                                            \
        (const __attribute__((address_space(1))) void*)(g),                      \
        (__attribute__((address_space(3))) void*)(l), 16, 0, 0)

// ---------------------------------------------------------------------------
// Cross-lane row swaps (gfx950 permlane*_swap), proven in R2.
// ---------------------------------------------------------------------------
__device__ __forceinline__ uint2v pl32(unsigned a, unsigned b) {
#if __has_builtin(__builtin_amdgcn_permlane32_swap)
    auto r = __builtin_amdgcn_permlane32_swap(a, b, false, false);
    uint2v o; o.x = (unsigned)r[0]; o.y = (unsigned)r[1]; return o;
#else
    unsigned as = (unsigned)__shfl_xor((int)a, 32, 64);
    unsigned bs = (unsigned)__shfl_xor((int)b, 32, 64);
    const bool hi = (threadIdx.x & 32) != 0;
    uint2v o; o.x = hi ? bs : a; o.y = hi ? b : as; return o;
#endif
}
__device__ __forceinline__ uint2v pl16(unsigned a, unsigned b) {
#if __has_builtin(__builtin_amdgcn_permlane16_swap)
    auto r = __builtin_amdgcn_permlane16_swap(a, b, false, false);
    uint2v o; o.x = (unsigned)r[0]; o.y = (unsigned)r[1]; return o;
#else
    unsigned as = (unsigned)__shfl_xor((int)a, 16, 64);
    unsigned bs = (unsigned)__shfl_xor((int)b, 16, 64);
    const bool odd = (threadIdx.x & 16) != 0;
    uint2v o; o.x = odd ? bs : a; o.y = odd ? b : as; return o;
#endif
}

// ---------------------------------------------------------------------------
// Fused prep: blocks [0,4096) cvt x->bf16; [4096,7168) Wqkv^T; [7168,8192) Wout^T.
// ---------------------------------------------------------------------------
__global__ __launch_bounds__(256) void prep(const float* __restrict__ x, u16* __restrict__ xb,
                                            const float* __restrict__ Wqkv, u16* __restrict__ WqkvT,
                                            const float* __restrict__ Wout, u16* __restrict__ WoutT) {
    __shared__ u16 t[32][33];
    int blk = blockIdx.x;
    if (blk < 4096) {
        const int i = blk * 256 + threadIdx.x;
        const floatx4 v = ((const floatx4*)x)[i];
        short4v o;
#pragma unroll
        for (int j = 0; j < 4; ++j) o[j] = (short)f2bf(v[j]);
        ((short4v*)xb)[i] = o;
        return;   // block-uniform: this block never reaches the barrier
    }
    const float* in; u16* out; int R, C, bx, by;
    if (blk < 4096 + 3072) { blk -= 4096; in = Wqkv; out = WqkvT; R = 1024; C = 3072; bx = blk % 96; by = blk / 96; }
    else                   { blk -= 7168; in = Wout; out = WoutT; R = 1024; C = 1024; bx = blk & 31; by = blk >> 5; }
    const int c0 = bx * 32, r0 = by * 32;
    const int xx = threadIdx.x & 31, yy = threadIdx.x >> 5;
#pragma unroll
    for (int i = 0; i < 32; i += 8) t[yy + i][xx] = f2bf(in[(size_t)(r0 + yy + i) * C + c0 + xx]);
    __syncthreads();
#pragma unroll
    for (int i = 0; i < 32; i += 8) out[(size_t)(c0 + yy + i) * R + r0 + xx] = t[xx][yy + i];
}

// ---------------------------------------------------------------------------
// qkv GEMM v2 (R5-proven): 128x128 tile, 4 waves, 3-buffer depth-2
// counted-vmcnt pipeline, conflict-free slot swizzle, 3 blocks/CU,
// XCD-bijective grid swizzle.
// ---------------------------------------------------------------------------
__global__ __launch_bounds__(256, 3) void gemm_qkv(const u16* __restrict__ A, const u16* __restrict__ Bt,
                                                   u16* __restrict__ C, u16* __restrict__ vtp) {
    constexpr int K = 1024, N = 3072;
    __shared__ u16 sA[3][128 * 32];   // 8 KB per buffer, 16B slots, swizzled
    __shared__ u16 sB[3][128 * 32];
    const int tid = threadIdx.x;
    const int lane = tid & 63, wave = tid >> 6;
    const int l15 = lane & 15, quad = lane >> 4;
    const int bid = blockIdx.x;
    const int sw = (bid & 7) * 96 + (bid >> 3);   // bijective XCD chunking
    const int bx = sw % 24, by = sw / 24;
    const int row0 = by * 128, col0 = bx * 128;
    const int wm = (wave & 1) * 64, wn = (wave >> 1) * 64;

    // staging: slot idx = it*256+tid; r=idx>>2, b=idx&3, logical chunk c=b^((r>>1)&3)
    const u16* aq[2]; const u16* bq[2]; int lo[2];
#pragma unroll
    for (int it = 0; it < 2; ++it) {
        const int idx = it * 256 + tid;
        const int r = idx >> 2, bb = idx & 3;
        const int c = bb ^ ((r >> 1) & 3);
        aq[it] = A + (size_t)(row0 + r) * K + c * 8;
        bq[it] = Bt + (size_t)(col0 + r) * K + c * 8;
        lo[it] = idx * 8;   // u16 units (16B per slot)
    }
    auto stage = [&](int bufi) {   // 4 GLDS16/thread per 32-K step
#pragma unroll
        for (int it = 0; it < 2; ++it) {
            GLDS16(aq[it], &sA[bufi][lo[it]]);
            GLDS16(bq[it], &sB[bufi][lo[it]]);
            aq[it] += 32; bq[it] += 32;
        }
    };

    floatx4 acc[4][4] = {};   // 64 VGPR accumulator (64x64 per wave)
    stage(0); stage(1);
    int bc = 0, bn = 1, bs = 2;
    for (int kc = 0; kc < 32; ++kc) {
        if (kc < 31) asm volatile("s_waitcnt vmcnt(4)" ::: "memory");  // drain stage(kc) only
        else         asm volatile("s_waitcnt vmcnt(0)" ::: "memory");
        __builtin_amdgcn_s_barrier();
        asm volatile("" ::: "memory");
        __builtin_amdgcn_sched_barrier(0);
        if (kc + 2 < 32) stage(bs);            // buffer computed at kc-1: reads done by barrier

        const u16* sa = sA[bc];
        const u16* sb = sB[bc];
        __builtin_amdgcn_s_setprio(1);
        bf16x8 af[4], bfr[4];
#pragma unroll
        for (int j = 0; j < 4; ++j) {
            const int r = wn + j * 16 + l15;
            const int s = r * 4 + (quad ^ ((r >> 1) & 3));
            bfr[j] = *(const bf16x8*)(sb + s * 8);
        }
#pragma unroll
        for (int i = 0; i < 4; ++i) {
            const int r = wm + i * 16 + l15;
            const int s = r * 4 + (quad ^ ((r >> 1) & 3));
            af[i] = *(const bf16x8*)(sa + s * 8);
        }
#pragma unroll
        for (int i = 0; i < 4; ++i)
#pragma unroll
            for (int j = 0; j < 4; ++j)
                acc[i][j] = __builtin_amdgcn_mfma_f32_16x16x32_bf16(af[i], bfr[j], acc[i][j], 0, 0, 0);
        __builtin_amdgcn_s_setprio(0);
        int t_ = bc; bc = bn; bn = bs; bs = t_;   // rotate buffers
    }
    // epilogue: h (bf16) + V^T side-output (pre-scaled 0.125)
#pragma unroll
    for (int i = 0; i < 4; ++i) {
#pragma unroll
        for (int j = 0; j < 4; ++j) {
            const int col = col0 + wn + j * 16 + l15;
            const int row = row0 + wm + i * 16 + quad * 4;
#pragma unroll
            for (int r = 0; r < 4; ++r)
                C[(size_t)(row + r) * N + col] = f2bf(acc[i][j][r]);
            if (col0 >= 2048) {   // V block: transposed+scaled copy
                short4v pk;
#pragma unroll
                for (int r = 0; r < 4; ++r) pk[r] = (short)f2bf(acc[i][j][r] * 0.125f);
                const int bb2 = row >> 11, s = row & 2047;
                const int hd = (col - 2048) >> 6, dh = col & 63;
                *(short4v*)(vtp + ((size_t)(bb2 * 16 + hd) * 64 + dh) * 2048 + s) = pk;
            }
        }
    }
}

// ---------------------------------------------------------------------------
// Out-proj GEMM v2 (R6): 3-buffer depth-2 counted vmcnt, conflict-free
// swizzle, XCD-bijective grid swizzle. TM=128, BN=64, 2 blocks/CU.
// ---------------------------------------------------------------------------
__global__ __launch_bounds__(256, 2) void gemm_out(const u16* __restrict__ A, const u16* __restrict__ Bt,
                                                   float* __restrict__ C, const float* __restrict__ bias) {
    constexpr int K = 1024, N = 1024;
    __shared__ u16 sA[3][128 * 32];   // 8 KB per buffer
    __shared__ u16 sB[3][64 * 32];    // 4 KB per buffer
    const int tid = threadIdx.x;
    const int lane = tid & 63, wave = tid >> 6;
    const int l15 = lane & 15, quad = lane >> 4;
    const int bid = blockIdx.x;
    const int sw = (bid & 7) * 64 + (bid >> 3);   // bijective XCD chunking
    const int bx = sw & 15, by = sw >> 4;
    const int row0 = by * 128, col0 = bx * 64;
    const int wm = (wave & 1) * 64, wn = (wave >> 1) * 32;

    const u16* aq[2]; const u16* bq; int lo[2], lob;
#pragma unroll
    for (int it = 0; it < 2; ++it) {
        const int idx = it * 256 + tid;
        const int r = idx >> 2, bb = idx & 3;
        const int c = bb ^ ((r >> 1) & 3);
        aq[it] = A + (size_t)(row0 + r) * K + c * 8;
        lo[it] = idx * 8;
    }
    {
        const int r = tid >> 2, bb = tid & 3;
        const int c = bb ^ ((r >> 1) & 3);
        bq = Bt + (size_t)(col0 + r) * K + c * 8;
        lob = tid * 8;
    }
    auto stage = [&](int bufi) {   // 3 GLDS16/thread per 32-K step
        GLDS16(aq[0], &sA[bufi][lo[0]]); aq[0] += 32;
        GLDS16(aq[1], &sA[bufi][lo[1]]); aq[1] += 32;
        GLDS16(bq, &sB[bufi][lob]); bq += 32;
    };

    floatx4 acc[4][2] = {};   // 32 VGPR accumulator (64x32 per wave)
    stage(0); stage(1);
    int bc = 0, bn = 1, bs = 2;
    for (int kc = 0; kc < 32; ++kc) {
        if (kc < 31) asm volatile("s_waitcnt vmcnt(3)" ::: "memory");  // drain stage(kc) only
        else         asm volatile("s_waitcnt vmcnt(0)" ::: "memory");
        __builtin_amdgcn_s_barrier();
        asm volatile("" ::: "memory");
        __builtin_amdgcn_sched_barrier(0);
        if (kc + 2 < 32) stage(bs);

        const u16* sa = sA[bc];
        const u16* sb = sB[bc];
        __builtin_amdgcn_s_setprio(1);
        bf16x8 af[4], bfr[2];
#pragma unroll
        for (int j = 0; j < 2; ++j) {
            const int r = wn + j * 16 + l15;
            const int s = r * 4 + (quad ^ ((r >> 1) & 3));
            bfr[j] = *(const bf16x8*)(sb + s * 8);
        }
#pragma unroll
        for (int i = 0; i < 4; ++i) {
            const int r = wm + i * 16 + l15;
            const int s = r * 4 + (quad ^ ((r >> 1) & 3));
            af[i] = *(const bf16x8*)(sa + s * 8);
        }
#pragma unroll
        for (int i = 0; i < 4; ++i)
#pragma unroll
            for (int j = 0; j < 2; ++j)
                acc[i][j] = __builtin_amdgcn_mfma_f32_16x16x32_bf16(af[i], bfr[j], acc[i][j], 0, 0, 0);
        __builtin_amdgcn_s_setprio(0);
        int t_ = bc; bc = bn; bn = bs; bs = t_;
    }
#pragma unroll
    for (int i = 0; i < 4; ++i) {
#pragma unroll
        for (int j = 0; j < 2; ++j) {
            const int col = col0 + wn + j * 16 + l15;
            const int row = row0 + wm + i * 16 + quad * 4;
            const float b = bias[col];
#pragma unroll
            for (int r = 0; r < 4; ++r)
                C[(size_t)(row + r) * N + col] = acc[i][j][r] + b;
        }
    }
}

// ---------------------------------------------------------------------------
// relu(S) pack to 4 bf16 (uint2): round-ties-away (+0x8000>>16), kept in regs.
// ---------------------------------------------------------------------------
__device__ __forceinline__ uint2v pack_relu(floatx4 s, bool diag, int kgb, int qg) {
    float v0 = fmaxf(s[0], 0.f), v1 = fmaxf(s[1], 0.f);
    float v2 = fmaxf(s[2], 0.f), v3 = fmaxf(s[3], 0.f);
    if (diag) {                      // block-uniform branch: only last chunk
        if (kgb + 0 > qg) v0 = 0.f;
        if (kgb + 1 > qg) v1 = 0.f;
        if (kgb + 2 > qg) v2 = 0.f;
        if (kgb + 3 > qg) v3 = 0.f;
    }
    uint2v p;
    p.x = ((__builtin_bit_cast(unsigned, v0) + 0x8000u) >> 16) |
          ((__builtin_bit_cast(unsigned, v1) + 0x8000u) & 0xffff0000u);
    p.y = ((__builtin_bit_cast(unsigned, v2) + 0x8000u) >> 16) |
          ((__builtin_bit_cast(unsigned, v3) + 0x8000u) & 0xffff0000u);
    return p;
}

// ---------------------------------------------------------------------------
// S^T frag -> PV A-frag transpose, in-register (proven R2).
// ---------------------------------------------------------------------------
__device__ __forceinline__ bf16x8 pfrag(uint2v A, uint2v B) {
    uint2v gx = pl32(A.x, B.x);
    uint2v dx = pl16(gx.x, gx.y);   // dx.x = d0, dx.y = d2
    uint2v gy = pl32(A.y, B.y);
    uint2v dy = pl16(gy.x, gy.y);   // dy.x = d1, dy.y = d3
    uint4v w; w.x = dx.x; w.y = dy.x; w.z = dx.y; w.w = dy.y;
    return __builtin_bit_cast(bf16x8, w);
}

// ---------------------------------------------------------------------------
// Causal ReLU attention, KEY-SPLIT waves (R3) at 4 BLOCKS/CU (R9):
// single 32 KB K/V buffer (no prefetch) -- with the whole 1024-block grid
// co-resident (4 waves/SIMD), cross-block TLP hides stage latency, the
// mechanism that fixed the GEMM in R5. Per chunk: barrier (reads of kc-1
// done) -> stage -> vmcnt(0) -> barrier -> compute. Reduction scratch
// shrunk to red[2] (34.8 KB union) via two-phase cross-wave reduction.
// ---------------------------------------------------------------------------
__global__ __launch_bounds__(256, 4) void relu_attn(const u16* __restrict__ h, const u16* __restrict__ vt,
                                                    float* __restrict__ o) {
    union SM {
        struct { u16 K[128 * 64]; u16 V[64 * 128]; } kv;  // 32 KB, swizzled
        float red[2][64 * 68];                            // 34.8 KB, [w][d][q pad68]
    };
    __shared__ SM sm;
    const int bid = blockIdx.x;
    const int pr = bid >> 5;            // 0 = heaviest, dispatched first
    const int bh = bid & 31;
    const int qt64 = 31 - pr;           // 64-query supertile index
    const int b = bh >> 4, hd = bh & 15;
    const int tid = threadIdx.x, lane = tid & 63, wave = tid >> 6;
    const int l15 = lane & 15, quad = lane >> 4;
    const int nc = (qt64 >> 1) + 1;     // 128-key chunks (last may be half-masked)

    // Q B-frags for ALL 64 queries of the supertile: [qt][ks] (32 VGPR)
    const int qrow0 = b * 2048 + qt64 * 64;
    bf16x8 qf[4][2];
#pragma unroll
    for (int qt = 0; qt < 4; ++qt)
#pragma unroll
        for (int ks = 0; ks < 2; ++ks)
            qf[qt][ks] = *(const bf16x8*)(h + (size_t)(qrow0 + qt * 16 + l15) * 3072 + hd * 64 + ks * 32 + quad * 8);

    floatx4 acc[4][4] = {};   // [qt][nt]: partial O[q][d] over this wave's keys

    const u16* kbase = h + (size_t)(b * 2048) * 3072 + 1024 + hd * 64;
    const u16* vbase = vt + (size_t)bh * 64 * 2048;

    // staging pointers: 4 K-rounds + 4 V-rounds of GLDS16 per thread per chunk
    const u16* kq[4]; const u16* vq[4]; int klo[4], vlo[4];
#pragma unroll
    for (int it = 0; it < 4; ++it) {
        const int idx = it * 256 + tid;
        { const int r = idx >> 3, c = idx & 7, cg = c ^ (r & 7);       // K: row=key(128), 8 blocks
          kq[it] = kbase + (size_t)r * 3072 + cg * 8; klo[it] = idx * 8; }
        { const int r = idx >> 4, c = idx & 15, cg = c ^ (r & 15);     // V: row=dh(64), 16 blocks
          vq[it] = vbase + (size_t)r * 2048 + cg * 8; vlo[it] = idx * 8; }
    }

    for (int kc = 0; kc < nc; ++kc) {
        __builtin_amdgcn_s_barrier();        // all waves done reading chunk kc-1
        asm volatile("" ::: "memory");
        // stage chunk kc into the single buffer (8 GLDS16/thread)
#pragma unroll
        for (int it = 0; it < 4; ++it) { GLDS16(kq[it], &sm.kv.K[klo[it]]); kq[it] += 128 * 3072; }
#pragma unroll
        for (int it = 0; it < 4; ++it) { GLDS16(vq[it], &sm.kv.V[vlo[it]]); vq[it] += 128; }
        asm volatile("s_waitcnt vmcnt(0)" ::: "memory");
        __builtin_amdgcn_s_barrier();        // chunk kc visible to all waves
        asm volatile("" ::: "memory");
        __builtin_amdgcn_sched_barrier(0);

        const u16* sK = sm.kv.K;
        const u16* sV = sm.kv.V;
        __builtin_amdgcn_s_setprio(1);
        // K A-frags: wave's 32 keys -> [kt][ks]  (4 x ds_read_b128)
        bf16x8 kf[2][2];
#pragma unroll
        for (int kt = 0; kt < 2; ++kt)
#pragma unroll
            for (int ks = 0; ks < 2; ++ks) {
                const int row = wave * 32 + kt * 16 + l15;
                const int blk = (quad + ks * 4) ^ (row & 7);
                kf[kt][ks] = *(const bf16x8*)(sK + row * 64 + blk * 8);
            }
        // QK: S^T[32k][64q] per wave
        const floatx4 z = {0.f, 0.f, 0.f, 0.f};
        floatx4 s[2][4];
#pragma unroll
        for (int kt = 0; kt < 2; ++kt)
#pragma unroll
            for (int qt = 0; qt < 4; ++qt) {
                floatx4 t = __builtin_amdgcn_mfma_f32_16x16x32_bf16(kf[kt][0], qf[qt][0], z, 0, 0, 0);
                s[kt][qt] = __builtin_amdgcn_mfma_f32_16x16x32_bf16(kf[kt][1], qf[qt][1], t, 0, 0, 0);
            }
        // relu + causal mask (last chunk only) + pack
        const bool last = (kc == nc - 1);
        uint2v p[2][4];
#pragma unroll
        for (int kt = 0; kt < 2; ++kt)
#pragma unroll
            for (int qt = 0; qt < 4; ++qt)
                p[kt][qt] = pack_relu(s[kt][qt], last,
                                      kc * 128 + wave * 32 + kt * 16 + quad * 4,
                                      qt64 * 64 + qt * 16 + l15);
        // V B-frags: wave's 32 keys x 64 dh -> [nt]  (4 x ds_read_b128)
        bf16x8 vf[4];
#pragma unroll
        for (int nt = 0; nt < 4; ++nt) {
            const int row = nt * 16 + l15;
            const int blk = (wave * 4 + quad) ^ (row & 15);
            vf[nt] = *(const bf16x8*)(sV + row * 128 + blk * 8);
        }
        // PV: partial O += P[64q][32k] . V[32k][64d]
#pragma unroll
        for (int qt = 0; qt < 4; ++qt) {
            const bf16x8 pa = pfrag(p[0][qt], p[1][qt]);
#pragma unroll
            for (int nt = 0; nt < 4; ++nt)
                acc[qt][nt] = __builtin_amdgcn_mfma_f32_16x16x32_bf16(pa, vf[nt], acc[qt][nt], 0, 0, 0);
        }
        __builtin_amdgcn_s_setprio(0);
    }

    // ---- two-phase cross-wave reduction of partial O (once per block) ----
    __syncthreads();   // all waves done reading kv before overwrite with red
    if (wave < 2) {    // waves 0,1 write their partials
        float* rw = sm.red[wave];
#pragma unroll
        for (int qt = 0; qt < 4; ++qt)
#pragma unroll
            for (int nt = 0; nt < 4; ++nt) {
                const int d = nt * 16 + l15, q = qt * 16 + quad * 4;
                *(floatx4*)(rw + d * 68 + q) = acc[qt][nt];
            }
    }
    __syncthreads();
    if (wave >= 2) {   // waves 2,3 add into red[wave-2]
        float* rw = sm.red[wave - 2];
#pragma unroll
        for (int qt = 0; qt < 4; ++qt)
#pragma unroll
            for (int nt = 0; nt < 4; ++nt) {
                const int d = nt * 16 + l15, q = qt * 16 + quad * 4;
                floatx4 cur = *(const floatx4*)(rw + d * 68 + q);
                cur += acc[qt][nt];
                *(floatx4*)(rw + d * 68 + q) = cur;
            }
    }
    __syncthreads();
    {
        const int d = lane;
#pragma unroll
        for (int j = 0; j < 4; ++j) {
            const int q = wave * 16 + j * 4;
            floatx4 a = *(const floatx4*)(sm.red[0] + d * 68 + q);
            a += *(const floatx4*)(sm.red[1] + d * 68 + q);
#pragma unroll
            for (int jj = 0; jj < 4; ++jj)
                o[(size_t)(qrow0 + q + jj) * 1024 + hd * 64 + d] = a[jj];
        }
    }
}

// ---------------------------------------------------------------------------
// Gated RMSNorm: one block per row of o [4096][1024] fp32 -> bf16
// ---------------------------------------------------------------------------
__global__ __launch_bounds__(256) void rms_gate(const float* __restrict__ o, const float* __restrict__ scale,
                                                const float* __restrict__ gate, u16* __restrict__ out) {
    const int row = blockIdx.x;
    const int tid = threadIdx.x;
    const floatx4* op = (const floatx4*)(o + (size_t)row * 1024);
    floatx4 v = op[tid];
    float ss = v[0] * v[0] + v[1] * v[1] + v[2] * v[2] + v[3] * v[3];
#pragma unroll
    for (int m = 32; m >= 1; m >>= 1) ss += __shfl_xor(ss, m, 64);
    __shared__ float red[4];
    if ((tid & 63) == 0) red[tid >> 6] = ss;
    __syncthreads();
    const float ms = (red[0] + red[1] + red[2] + red[3]) * (1.0f / 1024.0f);
    const float inv = rsqrtf(ms + 1e-7f);
    const int c = tid * 4;
#pragma unroll
    for (int j = 0; j < 4; ++j) {
        const float s = scale[c + j];
        const float g = gate[c + j];
        const float x = v[j];
        const float sig = 1.0f / (1.0f + __expf(-g * x));
        out[(size_t)row * 1024 + c + j] = f2bf(s * x * inv * sig);
    }
}

// ---------------------------------------------------------------------------
extern "C" void kernel_launch(void* const* d_in, const int* in_sizes, int n_in,
                              void* d_out, int out_size, void* d_ws, size_t ws_size,
                              hipStream_t stream) {
    const float* x     = (const float*)d_in[0];   // [2,2048,1024] fp32
    // d_in[1] = mem_mask: structurally causal, applied analytically
    const float* Wqkv  = (const float*)d_in[2];   // [1024,3072] fp32
    const float* Wout  = (const float*)d_in[3];   // [1024,1024] fp32
    const float* bout  = (const float*)d_in[4];   // [1024] fp32
    const float* scale = (const float*)d_in[5];   // [1024] fp32
    const float* gate  = (const float*)d_in[6];   // [1024] fp32
    float* out = (float*)d_out;                   // [2,2048,1024] fp32

    char* p = (char*)d_ws;
    u16* xb    = (u16*)p; p += (size_t)4096 * 1024 * 2;    // x in bf16
    u16* h     = (u16*)p; p += (size_t)4096 * 3072 * 2;    // qkv projection (bf16)
    u16* vt    = (u16*)p; p += (size_t)32 * 64 * 2048 * 2; // V^T [bh][dh][s], pre-scaled 0.125
    u16* WqkvT = (u16*)p; p += (size_t)3072 * 1024 * 2;
    u16* WoutT = (u16*)p; p += (size_t)1024 * 1024 * 2;
    float* oat = (float*)p; p += (size_t)4096 * 1024 * 4;  // attention out fp32
    u16* onorm = (u16*)p; p += (size_t)4096 * 1024 * 2;

    prep<<<8192, 256, 0, stream>>>(x, xb, Wqkv, WqkvT, Wout, WoutT);
    gemm_qkv<<<768, 256, 0, stream>>>(xb, WqkvT, h, vt);
    relu_attn<<<1024, 256, 0, stream>>>(h, vt, oat);
    rms_gate<<<4096, 256, 0, stream>>>(oat, scale, gate, onorm);
    gemm_out<<<512, 256, 0, stream>>>(onorm, WoutT, out, bout);
}

// Round 10
// 196.353 us; speedup vs baseline: 1.4873x; 1.4873x over previous
//
#include <hip/hip_runtime.h>
#include <hip/hip_bf16.h>

typedef unsigned short u16;
typedef __attribute__((ext_vector_type(8))) short bf16x8;
typedef __attribute__((ext_vector_type(4))) short short4v;
typedef __attribute__((ext_vector_type(4))) float floatx4;
typedef __attribute__((ext_vector_type(2))) unsigned uint2v;
typedef __attribute__((ext_vector_type(4))) unsigned uint4v;

__device__ __forceinline__ float bf2f(u16 u) {
    unsigned v = ((unsigned)u) << 16;
    return __builtin_bit_cast(float, v);
}
__device__ __forceinline__ u16 f2bf(float f) {
    unsigned u = __builtin_bit_cast(unsigned, f);
    u += 0x7fffu + ((u >> 16) & 1u);   // RNE
    return (u16)(u >> 16);
}

#define GLDS16(g, l)                                                             \
    __builtin_amdgcn_global_load_lds(                                            \
        (const __attribute__((address_space(1))) void*)(g),                      \
        (__attribute__((address_space(3))) void*)(l), 16, 0, 0)

// ---------------------------------------------------------------------------
// Cross-lane row swaps (gfx950 permlane*_swap), proven in R2.
// ---------------------------------------------------------------------------
__device__ __forceinline__ uint2v pl32(unsigned a, unsigned b) {
#if __has_builtin(__builtin_amdgcn_permlane32_swap)
    auto r = __builtin_amdgcn_permlane32_swap(a, b, false, false);
    uint2v o; o.x = (unsigned)r[0]; o.y = (unsigned)r[1]; return o;
#else
    unsigned as = (unsigned)__shfl_xor((int)a, 32, 64);
    unsigned bs = (unsigned)__shfl_xor((int)b, 32, 64);
    const bool hi = (threadIdx.x & 32) != 0;
    uint2v o; o.x = hi ? bs : a; o.y = hi ? b : as; return o;
#endif
}
__device__ __forceinline__ uint2v pl16(unsigned a, unsigned b) {
#if __has_builtin(__builtin_amdgcn_permlane16_swap)
    auto r = __builtin_amdgcn_permlane16_swap(a, b, false, false);
    uint2v o; o.x = (unsigned)r[0]; o.y = (unsigned)r[1]; return o;
#else
    unsigned as = (unsigned)__shfl_xor((int)a, 16, 64);
    unsigned bs = (unsigned)__shfl_xor((int)b, 16, 64);
    const bool odd = (threadIdx.x & 16) != 0;
    uint2v o; o.x = odd ? bs : a; o.y = odd ? b : as; return o;
#endif
}

// ---------------------------------------------------------------------------
// Fused prep: blocks [0,4096) cvt x->bf16; [4096,7168) Wqkv^T; [7168,8192) Wout^T.
// ---------------------------------------------------------------------------
__global__ __launch_bounds__(256) void prep(const float* __restrict__ x, u16* __restrict__ xb,
                                            const float* __restrict__ Wqkv, u16* __restrict__ WqkvT,
                                            const float* __restrict__ Wout, u16* __restrict__ WoutT) {
    __shared__ u16 t[32][33];
    int blk = blockIdx.x;
    if (blk < 4096) {
        const int i = blk * 256 + threadIdx.x;
        const floatx4 v = ((const floatx4*)x)[i];
        short4v o;
#pragma unroll
        for (int j = 0; j < 4; ++j) o[j] = (short)f2bf(v[j]);
        ((short4v*)xb)[i] = o;
        return;   // block-uniform: this block never reaches the barrier
    }
    const float* in; u16* out; int R, C, bx, by;
    if (blk < 4096 + 3072) { blk -= 4096; in = Wqkv; out = WqkvT; R = 1024; C = 3072; bx = blk % 96; by = blk / 96; }
    else                   { blk -= 7168; in = Wout; out = WoutT; R = 1024; C = 1024; bx = blk & 31; by = blk >> 5; }
    const int c0 = bx * 32, r0 = by * 32;
    const int xx = threadIdx.x & 31, yy = threadIdx.x >> 5;
#pragma unroll
    for (int i = 0; i < 32; i += 8) t[yy + i][xx] = f2bf(in[(size_t)(r0 + yy + i) * C + c0 + xx]);
    __syncthreads();
#pragma unroll
    for (int i = 0; i < 32; i += 8) out[(size_t)(c0 + yy + i) * R + r0 + xx] = t[xx][yy + i];
}

// ---------------------------------------------------------------------------
// qkv GEMM v2 (R5-proven): 128x128 tile, 4 waves, 3-buffer depth-2
// counted-vmcnt pipeline, conflict-free slot swizzle, 3 blocks/CU,
// XCD-bijective grid swizzle.
// ---------------------------------------------------------------------------
__global__ __launch_bounds__(256, 3) void gemm_qkv(const u16* __restrict__ A, const u16* __restrict__ Bt,
                                                   u16* __restrict__ C, u16* __restrict__ vtp) {
    constexpr int K = 1024, N = 3072;
    __shared__ u16 sA[3][128 * 32];   // 8 KB per buffer, 16B slots, swizzled
    __shared__ u16 sB[3][128 * 32];
    const int tid = threadIdx.x;
    const int lane = tid & 63, wave = tid >> 6;
    const int l15 = lane & 15, quad = lane >> 4;
    const int bid = blockIdx.x;
    const int sw = (bid & 7) * 96 + (bid >> 3);   // bijective XCD chunking
    const int bx = sw % 24, by = sw / 24;
    const int row0 = by * 128, col0 = bx * 128;
    const int wm = (wave & 1) * 64, wn = (wave >> 1) * 64;

    // staging: slot idx = it*256+tid; r=idx>>2, b=idx&3, logical chunk c=b^((r>>1)&3)
    const u16* aq[2]; const u16* bq[2]; int lo[2];
#pragma unroll
    for (int it = 0; it < 2; ++it) {
        const int idx = it * 256 + tid;
        const int r = idx >> 2, bb = idx & 3;
        const int c = bb ^ ((r >> 1) & 3);
        aq[it] = A + (size_t)(row0 + r) * K + c * 8;
        bq[it] = Bt + (size_t)(col0 + r) * K + c * 8;
        lo[it] = idx * 8;   // u16 units (16B per slot)
    }
    auto stage = [&](int bufi) {   // 4 GLDS16/thread per 32-K step
#pragma unroll
        for (int it = 0; it < 2; ++it) {
            GLDS16(aq[it], &sA[bufi][lo[it]]);
            GLDS16(bq[it], &sB[bufi][lo[it]]);
            aq[it] += 32; bq[it] += 32;
        }
    };

    floatx4 acc[4][4] = {};   // 64 VGPR accumulator (64x64 per wave)
    stage(0); stage(1);
    int bc = 0, bn = 1, bs = 2;
    for (int kc = 0; kc < 32; ++kc) {
        if (kc < 31) asm volatile("s_waitcnt vmcnt(4)" ::: "memory");  // drain stage(kc) only
        else         asm volatile("s_waitcnt vmcnt(0)" ::: "memory");
        __builtin_amdgcn_s_barrier();
        asm volatile("" ::: "memory");
        __builtin_amdgcn_sched_barrier(0);
        if (kc + 2 < 32) stage(bs);            // buffer computed at kc-1: reads done by barrier

        const u16* sa = sA[bc];
        const u16* sb = sB[bc];
        __builtin_amdgcn_s_setprio(1);
        bf16x8 af[4], bfr[4];
#pragma unroll
        for (int j = 0; j < 4; ++j) {
            const int r = wn + j * 16 + l15;
            const int s = r * 4 + (quad ^ ((r >> 1) & 3));
            bfr[j] = *(const bf16x8*)(sb + s * 8);
        }
#pragma unroll
        for (int i = 0; i < 4; ++i) {
            const int r = wm + i * 16 + l15;
            const int s = r * 4 + (quad ^ ((r >> 1) & 3));
            af[i] = *(const bf16x8*)(sa + s * 8);
        }
#pragma unroll
        for (int i = 0; i < 4; ++i)
#pragma unroll
            for (int j = 0; j < 4; ++j)
                acc[i][j] = __builtin_amdgcn_mfma_f32_16x16x32_bf16(af[i], bfr[j], acc[i][j], 0, 0, 0);
        __builtin_amdgcn_s_setprio(0);
        int t_ = bc; bc = bn; bn = bs; bs = t_;   // rotate buffers
    }
    // epilogue: h (bf16) + V^T side-output (pre-scaled 0.125)
#pragma unroll
    for (int i = 0; i < 4; ++i) {
#pragma unroll
        for (int j = 0; j < 4; ++j) {
            const int col = col0 + wn + j * 16 + l15;
            const int row = row0 + wm + i * 16 + quad * 4;
#pragma unroll
            for (int r = 0; r < 4; ++r)
                C[(size_t)(row + r) * N + col] = f2bf(acc[i][j][r]);
            if (col0 >= 2048) {   // V block: transposed+scaled copy
                short4v pk;
#pragma unroll
                for (int r = 0; r < 4; ++r) pk[r] = (short)f2bf(acc[i][j][r] * 0.125f);
                const int bb2 = row >> 11, s = row & 2047;
                const int hd = (col - 2048) >> 6, dh = col & 63;
                *(short4v*)(vtp + ((size_t)(bb2 * 16 + hd) * 64 + dh) * 2048 + s) = pk;
            }
        }
    }
}

// ---------------------------------------------------------------------------
// Out-proj GEMM v2 (R6): 3-buffer depth-2 counted vmcnt, conflict-free
// swizzle, XCD-bijective grid swizzle. TM=128, BN=64, 2 blocks/CU.
// ---------------------------------------------------------------------------
__global__ __launch_bounds__(256, 2) void gemm_out(const u16* __restrict__ A, const u16* __restrict__ Bt,
                                                   float* __restrict__ C, const float* __restrict__ bias) {
    constexpr int K = 1024, N = 1024;
    __shared__ u16 sA[3][128 * 32];   // 8 KB per buffer
    __shared__ u16 sB[3][64 * 32];    // 4 KB per buffer
    const int tid = threadIdx.x;
    const int lane = tid & 63, wave = tid >> 6;
    const int l15 = lane & 15, quad = lane >> 4;
    const int bid = blockIdx.x;
    const int sw = (bid & 7) * 64 + (bid >> 3);   // bijective XCD chunking
    const int bx = sw & 15, by = sw >> 4;
    const int row0 = by * 128, col0 = bx * 64;
    const int wm = (wave & 1) * 64, wn = (wave >> 1) * 32;

    const u16* aq[2]; const u16* bq; int lo[2], lob;
#pragma unroll
    for (int it = 0; it < 2; ++it) {
        const int idx = it * 256 + tid;
        const int r = idx >> 2, bb = idx & 3;
        const int c = bb ^ ((r >> 1) & 3);
        aq[it] = A + (size_t)(row0 + r) * K + c * 8;
        lo[it] = idx * 8;
    }
    {
        const int r = tid >> 2, bb = tid & 3;
        const int c = bb ^ ((r >> 1) & 3);
        bq = Bt + (size_t)(col0 + r) * K + c * 8;
        lob = tid * 8;
    }
    auto stage = [&](int bufi) {   // 3 GLDS16/thread per 32-K step
        GLDS16(aq[0], &sA[bufi][lo[0]]); aq[0] += 32;
        GLDS16(aq[1], &sA[bufi][lo[1]]); aq[1] += 32;
        GLDS16(bq, &sB[bufi][lob]); bq += 32;
    };

    floatx4 acc[4][2] = {};   // 32 VGPR accumulator (64x32 per wave)
    stage(0); stage(1);
    int bc = 0, bn = 1, bs = 2;
    for (int kc = 0; kc < 32; ++kc) {
        if (kc < 31) asm volatile("s_waitcnt vmcnt(3)" ::: "memory");  // drain stage(kc) only
        else         asm volatile("s_waitcnt vmcnt(0)" ::: "memory");
        __builtin_amdgcn_s_barrier();
        asm volatile("" ::: "memory");
        __builtin_amdgcn_sched_barrier(0);
        if (kc + 2 < 32) stage(bs);

        const u16* sa = sA[bc];
        const u16* sb = sB[bc];
        __builtin_amdgcn_s_setprio(1);
        bf16x8 af[4], bfr[2];
#pragma unroll
        for (int j = 0; j < 2; ++j) {
            const int r = wn + j * 16 + l15;
            const int s = r * 4 + (quad ^ ((r >> 1) & 3));
            bfr[j] = *(const bf16x8*)(sb + s * 8);
        }
#pragma unroll
        for (int i = 0; i < 4; ++i) {
            const int r = wm + i * 16 + l15;
            const int s = r * 4 + (quad ^ ((r >> 1) & 3));
            af[i] = *(const bf16x8*)(sa + s * 8);
        }
#pragma unroll
        for (int i = 0; i < 4; ++i)
#pragma unroll
            for (int j = 0; j < 2; ++j)
                acc[i][j] = __builtin_amdgcn_mfma_f32_16x16x32_bf16(af[i], bfr[j], acc[i][j], 0, 0, 0);
        __builtin_amdgcn_s_setprio(0);
        int t_ = bc; bc = bn; bn = bs; bs = t_;
    }
#pragma unroll
    for (int i = 0; i < 4; ++i) {
#pragma unroll
        for (int j = 0; j < 2; ++j) {
            const int col = col0 + wn + j * 16 + l15;
            const int row = row0 + wm + i * 16 + quad * 4;
            const float b = bias[col];
#pragma unroll
            for (int r = 0; r < 4; ++r)
                C[(size_t)(row + r) * N + col] = acc[i][j][r] + b;
        }
    }
}

// ---------------------------------------------------------------------------
// relu(S) pack to 4 bf16 (uint2): round-ties-away (+0x8000>>16), kept in regs.
// ---------------------------------------------------------------------------
__device__ __forceinline__ uint2v pack_relu(floatx4 s, bool diag, int kgb, int qg) {
    float v0 = fmaxf(s[0], 0.f), v1 = fmaxf(s[1], 0.f);
    float v2 = fmaxf(s[2], 0.f), v3 = fmaxf(s[3], 0.f);
    if (diag) {                      // block-uniform branch: only last chunk
        if (kgb + 0 > qg) v0 = 0.f;
        if (kgb + 1 > qg) v1 = 0.f;
        if (kgb + 2 > qg) v2 = 0.f;
        if (kgb + 3 > qg) v3 = 0.f;
    }
    uint2v p;
    p.x = ((__builtin_bit_cast(unsigned, v0) + 0x8000u) >> 16) |
          ((__builtin_bit_cast(unsigned, v1) + 0x8000u) & 0xffff0000u);
    p.y = ((__builtin_bit_cast(unsigned, v2) + 0x8000u) >> 16) |
          ((__builtin_bit_cast(unsigned, v3) + 0x8000u) & 0xffff0000u);
    return p;
}

// ---------------------------------------------------------------------------
// S^T frag -> PV A-frag transpose, in-register (proven R2).
// ---------------------------------------------------------------------------
__device__ __forceinline__ bf16x8 pfrag(uint2v A, uint2v B) {
    uint2v gx = pl32(A.x, B.x);
    uint2v dx = pl16(gx.x, gx.y);   // dx.x = d0, dx.y = d2
    uint2v gy = pl32(A.y, B.y);
    uint2v dy = pl16(gy.x, gy.y);   // dy.x = d1, dy.y = d3
    uint4v w; w.x = dx.x; w.y = dy.x; w.z = dx.y; w.w = dy.y;
    return __builtin_bit_cast(bf16x8, w);
}

// ---------------------------------------------------------------------------
// Causal ReLU attention, KEY-SPLIT waves (R3/R6-proven, session-best config):
// 1024 blocks = 32 q-supertiles x 32 bh; bid%8 = bh%8 so all blocks of a
// head share an XCD -> head K/V (~0.5 MB) stays L2-resident (FETCH ~12 MB).
// 2-buffer 64KB LDS, depth-1 prefetch, single vmcnt(0)+barrier per chunk,
// 2 blocks/CU. R8 (2-sub-phase) was neutral; R9 (4 blk/CU) thrashed L2.
// ---------------------------------------------------------------------------
__global__ __launch_bounds__(256, 2) void relu_attn(const u16* __restrict__ h, const u16* __restrict__ vt,
                                                    float* __restrict__ o) {
    union SM {
        struct { u16 K[2][128 * 64]; u16 V[2][64 * 128]; } kv;  // 64 KB, swizzled
        float red[4][64 * 68];                                  // 69.6 KB, [w][d][q pad68]
    };
    __shared__ SM sm;
    const int bid = blockIdx.x;
    const int pr = bid >> 5;            // 0 = heaviest, dispatched first
    const int bh = bid & 31;
    const int qt64 = 31 - pr;           // 64-query supertile index
    const int b = bh >> 4, hd = bh & 15;
    const int tid = threadIdx.x, lane = tid & 63, wave = tid >> 6;
    const int l15 = lane & 15, quad = lane >> 4;
    const int nc = (qt64 >> 1) + 1;     // 128-key chunks (last may be half-masked)

    // Q B-frags for ALL 64 queries of the supertile: [qt][ks] (32 VGPR)
    const int qrow0 = b * 2048 + qt64 * 64;
    bf16x8 qf[4][2];
#pragma unroll
    for (int qt = 0; qt < 4; ++qt)
#pragma unroll
        for (int ks = 0; ks < 2; ++ks)
            qf[qt][ks] = *(const bf16x8*)(h + (size_t)(qrow0 + qt * 16 + l15) * 3072 + hd * 64 + ks * 32 + quad * 8);

    floatx4 acc[4][4] = {};   // [qt][nt]: partial O[q][d] over this wave's keys

    const u16* kbase = h + (size_t)(b * 2048) * 3072 + 1024 + hd * 64;
    const u16* vbase = vt + (size_t)bh * 64 * 2048;

    // staging pointers: 4 K-rounds + 4 V-rounds of GLDS16 per thread per chunk
    const u16* kq[4]; const u16* vq[4]; int klo[4], vlo[4];
#pragma unroll
    for (int it = 0; it < 4; ++it) {
        const int idx = it * 256 + tid;
        { const int r = idx >> 3, c = idx & 7, cg = c ^ (r & 7);       // K: row=key(128), 8 blocks
          kq[it] = kbase + (size_t)r * 3072 + cg * 8; klo[it] = idx * 8; }
        { const int r = idx >> 4, c = idx & 15, cg = c ^ (r & 15);     // V: row=dh(64), 16 blocks
          vq[it] = vbase + (size_t)r * 2048 + cg * 8; vlo[it] = idx * 8; }
    }
    auto stage = [&](int bufi) {   // 8 GLDS16/thread per 128-key chunk
#pragma unroll
        for (int it = 0; it < 4; ++it) { GLDS16(kq[it], &sm.kv.K[bufi][klo[it]]); kq[it] += 128 * 3072; }
#pragma unroll
        for (int it = 0; it < 4; ++it) { GLDS16(vq[it], &sm.kv.V[bufi][vlo[it]]); vq[it] += 128; }
    };

    stage(0);
    int buf = 0;
    for (int kc = 0; kc < nc; ++kc) {
        asm volatile("s_waitcnt vmcnt(0)" ::: "memory");
        __builtin_amdgcn_s_barrier();           // all waves' stage(kc) visible
        asm volatile("" ::: "memory");
        __builtin_amdgcn_sched_barrier(0);
        if (kc + 1 < nc) stage(buf ^ 1);        // prefetch during compute

        const u16* sK = sm.kv.K[buf];
        const u16* sV = sm.kv.V[buf];
        __builtin_amdgcn_s_setprio(1);
        // K A-frags: wave's 32 keys -> [kt][ks]  (4 x ds_read_b128)
        bf16x8 kf[2][2];
#pragma unroll
        for (int kt = 0; kt < 2; ++kt)
#pragma unroll
            for (int ks = 0; ks < 2; ++ks) {
                const int row = wave * 32 + kt * 16 + l15;
                const int blk = (quad + ks * 4) ^ (row & 7);
                kf[kt][ks] = *(const bf16x8*)(sK + row * 64 + blk * 8);
            }
        // QK: S^T[32k][64q] per wave
        const floatx4 z = {0.f, 0.f, 0.f, 0.f};
        floatx4 s[2][4];
#pragma unroll
        for (int kt = 0; kt < 2; ++kt)
#pragma unroll
            for (int qt = 0; qt < 4; ++qt) {
                floatx4 t = __builtin_amdgcn_mfma_f32_16x16x32_bf16(kf[kt][0], qf[qt][0], z, 0, 0, 0);
                s[kt][qt] = __builtin_amdgcn_mfma_f32_16x16x32_bf16(kf[kt][1], qf[qt][1], t, 0, 0, 0);
            }
        // relu + causal mask (last chunk only) + pack
        const bool last = (kc == nc - 1);
        uint2v p[2][4];
#pragma unroll
        for (int kt = 0; kt < 2; ++kt)
#pragma unroll
            for (int qt = 0; qt < 4; ++qt)
                p[kt][qt] = pack_relu(s[kt][qt], last,
                                      kc * 128 + wave * 32 + kt * 16 + quad * 4,
                                      qt64 * 64 + qt * 16 + l15);
        // V B-frags: wave's 32 keys x 64 dh -> [nt]  (4 x ds_read_b128)
        bf16x8 vf[4];
#pragma unroll
        for (int nt = 0; nt < 4; ++nt) {
            const int row = nt * 16 + l15;
            const int blk = (wave * 4 + quad) ^ (row & 15);
            vf[nt] = *(const bf16x8*)(sV + row * 128 + blk * 8);
        }
        // PV: partial O += P[64q][32k] . V[32k][64d]
#pragma unroll
        for (int qt = 0; qt < 4; ++qt) {
            const bf16x8 pa = pfrag(p[0][qt], p[1][qt]);
#pragma unroll
            for (int nt = 0; nt < 4; ++nt)
                acc[qt][nt] = __builtin_amdgcn_mfma_f32_16x16x32_bf16(pa, vf[nt], acc[qt][nt], 0, 0, 0);
        }
        __builtin_amdgcn_s_setprio(0);
        buf ^= 1;
    }

    // ---- cross-wave reduction of partial O (once per block) ----
    __syncthreads();   // all waves done reading kv before overwrite with red
    float* rw = sm.red[wave];
#pragma unroll
    for (int qt = 0; qt < 4; ++qt)
#pragma unroll
        for (int nt = 0; nt < 4; ++nt) {
            const int d = nt * 16 + l15, q = qt * 16 + quad * 4;
            *(floatx4*)(rw + d * 68 + q) = acc[qt][nt];
        }
    __syncthreads();
    {
        const int d = lane;
#pragma unroll
        for (int j = 0; j < 4; ++j) {
            const int q = wave * 16 + j * 4;
            floatx4 a = *(const floatx4*)(sm.red[0] + d * 68 + q);
            a += *(const floatx4*)(sm.red[1] + d * 68 + q);
            a += *(const floatx4*)(sm.red[2] + d * 68 + q);
            a += *(const floatx4*)(sm.red[3] + d * 68 + q);
#pragma unroll
            for (int jj = 0; jj < 4; ++jj)
                o[(size_t)(qrow0 + q + jj) * 1024 + hd * 64 + d] = a[jj];
        }
    }
}

// ---------------------------------------------------------------------------
// Gated RMSNorm: one block per row of o [4096][1024] fp32 -> bf16
// ---------------------------------------------------------------------------
__global__ __launch_bounds__(256) void rms_gate(const float* __restrict__ o, const float* __restrict__ scale,
                                                const float* __restrict__ gate, u16* __restrict__ out) {
    const int row = blockIdx.x;
    const int tid = threadIdx.x;
    const floatx4* op = (const floatx4*)(o + (size_t)row * 1024);
    floatx4 v = op[tid];
    float ss = v[0] * v[0] + v[1] * v[1] + v[2] * v[2] + v[3] * v[3];
#pragma unroll
    for (int m = 32; m >= 1; m >>= 1) ss += __shfl_xor(ss, m, 64);
    __shared__ float red[4];
    if ((tid & 63) == 0) red[tid >> 6] = ss;
    __syncthreads();
    const float ms = (red[0] + red[1] + red[2] + red[3]) * (1.0f / 1024.0f);
    const float inv = rsqrtf(ms + 1e-7f);
    const int c = tid * 4;
#pragma unroll
    for (int j = 0; j < 4; ++j) {
        const float s = scale[c + j];
        const float g = gate[c + j];
        const float x = v[j];
        const float sig = 1.0f / (1.0f + __expf(-g * x));
        out[(size_t)row * 1024 + c + j] = f2bf(s * x * inv * sig);
    }
}

// ---------------------------------------------------------------------------
extern "C" void kernel_launch(void* const* d_in, const int* in_sizes, int n_in,
                              void* d_out, int out_size, void* d_ws, size_t ws_size,
                              hipStream_t stream) {
    const float* x     = (const float*)d_in[0];   // [2,2048,1024] fp32
    // d_in[1] = mem_mask: structurally causal, applied analytically
    const float* Wqkv  = (const float*)d_in[2];   // [1024,3072] fp32
    const float* Wout  = (const float*)d_in[3];   // [1024,1024] fp32
    const float* bout  = (const float*)d_in[4];   // [1024] fp32
    const float* scale = (const float*)d_in[5];   // [1024] fp32
    const float* gate  = (const float*)d_in[6];   // [1024] fp32
    float* out = (float*)d_out;                   // [2,2048,1024] fp32

    char* p = (char*)d_ws;
    u16* xb    = (u16*)p; p += (size_t)4096 * 1024 * 2;    // x in bf16
    u16* h     = (u16*)p; p += (size_t)4096 * 3072 * 2;    // qkv projection (bf16)
    u16* vt    = (u16*)p; p += (size_t)32 * 64 * 2048 * 2; // V^T [bh][dh][s], pre-scaled 0.125
    u16* WqkvT = (u16*)p; p += (size_t)3072 * 1024 * 2;
    u16* WoutT = (u16*)p; p += (size_t)1024 * 1024 * 2;
    float* oat = (float*)p; p += (size_t)4096 * 1024 * 4;  // attention out fp32
    u16* onorm = (u16*)p; p += (size_t)4096 * 1024 * 2;

    prep<<<8192, 256, 0, stream>>>(x, xb, Wqkv, WqkvT, Wout, WoutT);
    gemm_qkv<<<768, 256, 0, stream>>>(xb, WqkvT, h, vt);
    relu_attn<<<1024, 256, 0, stream>>>(h, vt, oat);
    rms_gate<<<4096, 256, 0, stream>>>(oat, scale, gate, onorm);
    gemm_out<<<512, 256, 0, stream>>>(onorm, WoutT, out, bout);
}